// Round 11
// baseline (730.974 us; speedup 1.0000x reference)
//
#include <hip/hip_runtime.h>
#include <stdint.h>

#define B_ 8
#define S_ 512
#define D_ 768
#define H_ 12
#define DK_ 64
#define F_ 3072
#define L_ 4
#define NT_ (B_*S_)     // 4096 tokens
#define BH_ (B_*H_)     // 96 (b,h) pairs
#define DQKV_ 2304      // fused q|k|v width

typedef __bf16 bf16x8 __attribute__((ext_vector_type(8)));
typedef float f32x4 __attribute__((ext_vector_type(4)));

static __device__ __forceinline__ unsigned short f2b(float f){
  union { float f; unsigned u; } x; x.f = f;
  unsigned r = x.u + 0x7fffu + ((x.u >> 16) & 1u);   // RNE, finite values
  return (unsigned short)(r >> 16);
}
static __device__ __forceinline__ float b2f(unsigned short u){
  union { unsigned u; float f; } x; x.u = ((unsigned)u) << 16; return x.f;
}

static __device__ __forceinline__ void gload16(const void* g, void* l){
  __builtin_amdgcn_global_load_lds((const __attribute__((address_space(1))) void*)g,
                                   (__attribute__((address_space(3))) void*)l, 16, 0, 0);
}

static __device__ __forceinline__ float wsum(float v){
  #pragma unroll
  for (int off = 32; off; off >>= 1) v += __shfl_xor(v, off);
  return v;
}

// ---------------- weight transpose + f32->bf16: in[R][C] -> out[(rowBase+c)*R + r]
__global__ void wconv_kernel(const float* __restrict__ in, unsigned short* __restrict__ out,
                             int R, int C, size_t outLS, int rowBase){
  __shared__ float tile[64][33];
  const int l = blockIdx.z;
  in  += (size_t)l*R*C;
  out += (size_t)l*outLS;
  const int c0 = blockIdx.x*32, r0 = blockIdx.y*64;
  const int tx = threadIdx.x, ty = threadIdx.y;  // (32,8)
  #pragma unroll
  for (int i = 0; i < 8; ++i)
    tile[ty+8*i][tx] = in[(size_t)(r0+ty+8*i)*C + c0+tx];
  __syncthreads();
  #pragma unroll
  for (int p = 0; p < 4; ++p) {
    const int c = p*8 + ty;
    ushort2 u;
    u.x = f2b(tile[tx*2][c]);
    u.y = f2b(tile[tx*2+1][c]);
    *reinterpret_cast<ushort2*>(&out[(size_t)(rowBase + c0 + c)*R + r0 + tx*2]) = u;
  }
}

// ---------------- fused q|k|v weight transpose
__global__ void wconvqkv_kernel(const float* __restrict__ Wq, const float* __restrict__ Wk,
                                const float* __restrict__ Wv, unsigned short* __restrict__ out){
  __shared__ float tile[64][33];
  const int z = blockIdx.z;
  const int l = z / 3, which = z % 3;
  const float* in = (which == 0 ? Wq : which == 1 ? Wk : Wv) + (size_t)l*D_*D_;
  unsigned short* o = out + (size_t)l*DQKV_*D_;
  const int rowBase = which*D_;
  const int c0 = blockIdx.x*32, r0 = blockIdx.y*64;
  const int tx = threadIdx.x, ty = threadIdx.y;  // (32,8)
  #pragma unroll
  for (int i = 0; i < 8; ++i)
    tile[ty+8*i][tx] = in[(size_t)(r0+ty+8*i)*D_ + c0+tx];
  __syncthreads();
  #pragma unroll
  for (int p = 0; p < 4; ++p) {
    const int c = p*8 + ty;
    ushort2 u;
    u.x = f2b(tile[tx*2][c]);
    u.y = f2b(tile[tx*2+1][c]);
    *reinterpret_cast<ushort2*>(&o[(size_t)(rowBase + c0 + c)*D_ + r0 + tx*2]) = u;
  }
}

// ---------------- concat q|k|v biases -> [L][2304]
__global__ void bcat_kernel(const float* __restrict__ bq, const float* __restrict__ bk,
                            const float* __restrict__ bv, float* __restrict__ out){
  int i = blockIdx.x*256 + threadIdx.x;
  if (i >= L_*DQKV_) return;
  int l = i / DQKV_, c = i % DQKV_;
  float v = (c < D_) ? bq[l*D_ + c] : (c < 2*D_) ? bk[l*D_ + c - D_] : bv[l*D_ + c - 2*D_];
  out[i] = v;
}

// ---------------- sinusoidal PE table [S][D]
__global__ __launch_bounds__(256) void pe_kernel(float* __restrict__ pe){
  int u = blockIdx.x*256 + threadIdx.x;   // S*384 pairs
  if (u >= S_*384) return;
  int dp = u % 384, s = u / 384;
  int d0 = dp*2;
  float div = __expf((float)d0 * (-9.210340371976184f / 768.0f));
  float ang = (float)s * div;
  pe[(size_t)s*D_ + d0]     = sinf(ang);
  pe[(size_t)s*D_ + d0 + 1] = cosf(ang);
}

// ---------------- embedding + PE table; writes bf16 hb (residual stream is bf16)
__global__ __launch_bounds__(256) void embed_kernel(const int* __restrict__ ids,
                                                    const float* __restrict__ emb,
                                                    const float* __restrict__ pe,
                                                    unsigned short* __restrict__ hb){
  int u = blockIdx.x*256 + threadIdx.x;   // NT*192 float4 units
  if (u >= NT_*192) return;
  int c = u % 192, t = u / 192, s = t % S_;
  int id = ids[t];
  float4 e = reinterpret_cast<const float4*>(emb + (size_t)id*D_)[c];
  float4 p = reinterpret_cast<const float4*>(pe  + (size_t)s*D_)[c];
  ushort4 ub; ub.x = f2b(e.x+p.x); ub.y = f2b(e.y+p.y); ub.z = f2b(e.z+p.z); ub.w = f2b(e.w+p.w);
  reinterpret_cast<ushort4*>(hb + (size_t)t*D_)[c] = ub;
}

// ---------------- 128xTN bf16 MFMA GEMM, BK=64 double-buffer, ONE barrier/vmcnt/lgkm
// per 64-K step. Per iter t (buf b=t&1): vmcnt(0) [tile t landed; issued a full iter
// ago] -> s_barrier [data visible + buf b^1 readers done] -> 16 ds_read (both k-halves,
// straight-line, same reg names) -> stage(t+1 -> b^1) -> lgkm(0) -> 32 MFMA.
// A:[M][K], Bt:[N][K], XCD-swizzled 1D grid. KS: split-K. Output bf16 at outp+ks*M*N.
template<int TN, int KS, bool BIAS, bool RES, bool RELU>
__global__ __launch_bounds__(256)
void gemm_kernel(const unsigned short* __restrict__ A,
                 const unsigned short* __restrict__ Bt,
                 const float* __restrict__ bias,
                 const unsigned short* __restrict__ residB,
                 unsigned short* __restrict__ outp,
                 int M, int N, int K)
{
  constexpr int WN = TN/2;           // wave cols (2x2 wave grid)
  constexpr int JF = WN/16;          // n-frags per wave per k-half
  constexpr int BPASS = TN/32;       // B-tile 4KB passes (A is 4)
  __shared__ __attribute__((aligned(16))) unsigned short As[2][128*64];
  __shared__ __attribute__((aligned(16))) unsigned short Bs[2][TN*64];
  const int tid = threadIdx.x;
  const int w = tid >> 6, l = tid & 63;
  const int wm = w >> 1, wn = w & 1;
  const int c16 = l & 15, g = l >> 4;

  // bijective XCD swizzle (requires gridDim.x % 8 == 0)
  const int nwg = gridDim.x;
  const int cpx = nwg >> 3;
  const int sw  = (blockIdx.x & 7)*cpx + (blockIdx.x >> 3);
  const int nbx = N/TN;
  const int nby = M/128;
  const int bx = sw % nbx;
  const int t2 = sw / nbx;
  const int by = t2 % nby;
  const int ks = t2 / nby;          // 0..KS-1
  const int bm = by*128, bn = bx*TN;
  const int Klen = K / KS;
  const int kBeg = ks*Klen;
  const int nk = Klen >> 6;         // 64-K tiles; all call sites have nk == 12

  auto stage = [&](int buf, int k0){
    #pragma unroll
    for (int s = 0; s < 4; ++s) {            // A: 128 rows x 128B = 16KB
      const int x = s*4096 + tid*16;
      const int row = x >> 7, col = (x & 127) >> 1;
      gload16(A + (size_t)(bm+row)*K + k0 + col, (void*)(As[buf] + x/2));
    }
    #pragma unroll
    for (int s = 0; s < BPASS; ++s) {        // B: TN rows x 128B
      const int x = s*4096 + tid*16;
      const int row = x >> 7, col = (x & 127) >> 1;
      gload16(Bt + (size_t)(bn+row)*K + k0 + col, (void*)(Bs[buf] + x/2));
    }
  };

  f32x4 acc[4][JF] = {};

  stage(0, kBeg);

  for (int t = 0; t < nk; ++t) {
    const int b = t & 1;
    asm volatile("s_waitcnt vmcnt(0)" ::: "memory");   // tile t (own loads) landed
    __builtin_amdgcn_s_barrier();                      // all waves: data visible; b^1 free
    __builtin_amdgcn_sched_barrier(0);

    bf16x8 a0[4], b0[JF], a1[4], b1[JF];
    #pragma unroll
    for (int i = 0; i < 4; ++i)
      a0[i] = *reinterpret_cast<const bf16x8*>(&As[b][(wm*64 + i*16 + c16)*64 + g*8]);
    #pragma unroll
    for (int j = 0; j < JF; ++j)
      b0[j] = *reinterpret_cast<const bf16x8*>(&Bs[b][(wn*WN + j*16 + c16)*64 + g*8]);

    if (t + 1 < nk) stage(b ^ 1, kBeg + (t+1)*64);     // prefetch; hides under MFMA

    #pragma unroll
    for (int i = 0; i < 4; ++i)
      a1[i] = *reinterpret_cast<const bf16x8*>(&As[b][(wm*64 + i*16 + c16)*64 + 32 + g*8]);
    #pragma unroll
    for (int j = 0; j < JF; ++j)
      b1[j] = *reinterpret_cast<const bf16x8*>(&Bs[b][(wn*WN + j*16 + c16)*64 + 32 + g*8]);

    asm volatile("s_waitcnt lgkmcnt(0)" ::: "memory");
    __builtin_amdgcn_sched_barrier(0);

    __builtin_amdgcn_s_setprio(1);
    #pragma unroll
    for (int i = 0; i < 4; ++i)
      #pragma unroll
      for (int j = 0; j < JF; ++j)
        acc[i][j] = __builtin_amdgcn_mfma_f32_16x16x32_bf16(a0[i], b0[j], acc[i][j], 0, 0, 0);
    #pragma unroll
    for (int i = 0; i < 4; ++i)
      #pragma unroll
      for (int j = 0; j < JF; ++j)
        acc[i][j] = __builtin_amdgcn_mfma_f32_16x16x32_bf16(a1[i], b1[j], acc[i][j], 0, 0, 0);
    __builtin_amdgcn_s_setprio(0);
  }

  unsigned short* outB = outp + (size_t)ks*M*N;
  #pragma unroll
  for (int i = 0; i < 4; ++i) {
    #pragma unroll
    for (int e = 0; e < 4; ++e) {
      const int row = bm + wm*64 + i*16 + (l>>4)*4 + e;
      #pragma unroll
      for (int j = 0; j < JF; ++j) {
        const int col = bn + wn*WN + j*16 + (l&15);
        float v = acc[i][j][e];
        if constexpr (BIAS) v += bias[col];
        if constexpr (RES)  v += b2f(residB[(size_t)row*N + col]);
        if constexpr (RELU) v = fmaxf(v, 0.f);
        outB[(size_t)row*N + col] = f2b(v);
      }
    }
  }
}

// ---------------- V transpose per head: src[b,s,ld-strided, head hh] -> vt[(b*H+h), d, s]
__global__ void vtrans_kernel(const unsigned short* __restrict__ v,
                              unsigned short* __restrict__ vt, int ld){
  __shared__ unsigned short tile[32][33];
  const int z = blockIdx.z; const int b = z / H_, hh = z % H_;
  const int j0 = blockIdx.x*32;   // seq
  const int d0 = blockIdx.y*32;   // within head
  const int tx = threadIdx.x, ty = threadIdx.y;
  const unsigned short* src = v + (size_t)b*S_*ld + hh*DK_;
  #pragma unroll
  for (int i = 0; i < 4; ++i)
    tile[ty+8*i][tx] = src[(size_t)(j0+ty+8*i)*ld + d0+tx];
  __syncthreads();
  unsigned short* dst = vt + (size_t)z*DK_*S_;
  #pragma unroll
  for (int i = 0; i < 4; ++i)
    dst[(size_t)(d0+ty+8*i)*S_ + j0+tx] = tile[tx][ty+8*i];
}

// ---------------- fused flash attention: QK^T (swapped) -> online softmax -> PV
__global__ __launch_bounds__(256)
void fattn_kernel(const unsigned short* __restrict__ qkv,
                  const unsigned short* __restrict__ vt,
                  unsigned short* __restrict__ o)
{
  __shared__ __attribute__((aligned(16))) unsigned short Plds[4*4096]; // 4 waves x 8KB
  const int tid = threadIdx.x;
  const int w = tid >> 6, l = tid & 63;
  const int g = l >> 4, c16 = l & 15;
  const int z = blockIdx.y; const int b = z / H_, hh = z % H_;
  const int q0 = blockIdx.x*128 + w*32;

  const unsigned short* qp = qkv + (size_t)b*S_*DQKV_ + hh*DK_;
  const unsigned short* kp = qp + D_;
  const unsigned short* vv = vt + (size_t)z*DK_*S_;
  char* pbase = (char*)Plds + w*8192;

  // hoist Q fragments (B-operand: cols = q rows)
  bf16x8 qf[2][2];
  #pragma unroll
  for (int jf = 0; jf < 2; ++jf)
    #pragma unroll
    for (int kc = 0; kc < 2; ++kc)
      qf[jf][kc] = *reinterpret_cast<const bf16x8*>(qp + (size_t)(q0 + jf*16 + c16)*DQKV_ + kc*32 + g*8);

  f32x4 acc_o[2][4] = {};
  float m_run[2] = {-1e30f, -1e30f};
  float l_run[2] = {0.f, 0.f};

  for (int kb = 0; kb < S_/128; ++kb) {
    f32x4 acc_s[8][2] = {};
    #pragma unroll
    for (int kt = 0; kt < 8; ++kt) {
      bf16x8 af0 = *reinterpret_cast<const bf16x8*>(kp + (size_t)(kb*128 + kt*16 + c16)*DQKV_ + 0*32 + g*8);
      bf16x8 af1 = *reinterpret_cast<const bf16x8*>(kp + (size_t)(kb*128 + kt*16 + c16)*DQKV_ + 1*32 + g*8);
      #pragma unroll
      for (int jf = 0; jf < 2; ++jf) {
        acc_s[kt][jf] = __builtin_amdgcn_mfma_f32_16x16x32_bf16(af0, qf[jf][0], acc_s[kt][jf], 0, 0, 0);
        acc_s[kt][jf] = __builtin_amdgcn_mfma_f32_16x16x32_bf16(af1, qf[jf][1], acc_s[kt][jf], 0, 0, 0);
      }
    }
    float fac[2];
    #pragma unroll
    for (int jf = 0; jf < 2; ++jf) {
      float vmax = -1e30f;
      #pragma unroll
      for (int kt = 0; kt < 8; ++kt)
        #pragma unroll
        for (int e = 0; e < 4; ++e) {
          acc_s[kt][jf][e] *= 0.125f;
          vmax = fmaxf(vmax, acc_s[kt][jf][e]);
        }
      vmax = fmaxf(vmax, __shfl_xor(vmax, 16));
      vmax = fmaxf(vmax, __shfl_xor(vmax, 32));
      const float m_new = fmaxf(m_run[jf], vmax);
      fac[jf] = __expf(m_run[jf] - m_new);
      float ps = 0.f;
      #pragma unroll
      for (int kt = 0; kt < 8; ++kt)
        #pragma unroll
        for (int e = 0; e < 4; ++e) {
          float p = __expf(acc_s[kt][jf][e] - m_new);
          acc_s[kt][jf][e] = p;
          ps += p;
        }
      ps += __shfl_xor(ps, 16);
      ps += __shfl_xor(ps, 32);
      l_run[jf] = l_run[jf]*fac[jf] + ps;
      m_run[jf] = m_new;
      const int q = jf*16 + c16;
      #pragma unroll
      for (int kt = 0; kt < 8; ++kt) {
        uint2 val;
        val.x = (unsigned)f2b(acc_s[kt][jf][0]) | ((unsigned)f2b(acc_s[kt][jf][1]) << 16);
        val.y = (unsigned)f2b(acc_s[kt][jf][2]) | ((unsigned)f2b(acc_s[kt][jf][3]) << 16);
        int off = (q*256 + kt*32 + g*8) ^ ((q & 7) << 4);
        *reinterpret_cast<uint2*>(pbase + off) = val;
      }
    }
    #pragma unroll
    for (int jr = 0; jr < 2; ++jr)
      #pragma unroll
      for (int e = 0; e < 4; ++e) {
        const float fr = __shfl(fac[jr], g*4 + e);
        #pragma unroll
        for (int jd = 0; jd < 4; ++jd)
          acc_o[jr][jd][e] *= fr;
      }
    #pragma unroll
    for (int kc = 0; kc < 4; ++kc) {
      bf16x8 pa[2], vfr[4];
      #pragma unroll
      for (int jf = 0; jf < 2; ++jf) {
        const int q = jf*16 + c16;
        int off = (q*256 + kc*64 + g*16) ^ ((q & 7) << 4);
        pa[jf] = *reinterpret_cast<const bf16x8*>(pbase + off);
      }
      #pragma unroll
      for (int jd = 0; jd < 4; ++jd)
        vfr[jd] = *reinterpret_cast<const bf16x8*>(vv + (size_t)(jd*16 + c16)*S_ + kb*128 + kc*32 + g*8);
      #pragma unroll
      for (int jf = 0; jf < 2; ++jf)
        #pragma unroll
        for (int jd = 0; jd < 4; ++jd)
          acc_o[jf][jd] = __builtin_amdgcn_mfma_f32_16x16x32_bf16(pa[jf], vfr[jd], acc_o[jf][jd], 0, 0, 0);
    }
  }

  float invl[2] = {1.f/l_run[0], 1.f/l_run[1]};
  unsigned short* ob = o + (size_t)b*S_*D_ + hh*DK_;
  #pragma unroll
  for (int jr = 0; jr < 2; ++jr)
    #pragma unroll
    for (int e = 0; e < 4; ++e) {
      const float ir = __shfl(invl[jr], g*4 + e);
      const int r = q0 + jr*16 + g*4 + e;
      #pragma unroll
      for (int jd = 0; jd < 4; ++jd)
        ob[(size_t)r*D_ + jd*16 + c16] = f2b(acc_o[jr][jd][e] * ir);
    }
}

// ---------------- LayerNorm: wave per row. x = sum of NP bf16 partials (stride NT*D);
// EXTRA adds bf16 resid + broadcast f32 bias2. Writes bf16 hb; WF32 also writes f32 ho.
template<int NP, bool EXTRA, bool WF32>
__global__ __launch_bounds__(256)
void ln_kernel(const unsigned short* __restrict__ xb,
               const unsigned short* __restrict__ resid, const float* __restrict__ bias2,
               const float* __restrict__ g, const float* __restrict__ bta,
               float* __restrict__ ho, unsigned short* __restrict__ hb)
{
  const int w = threadIdx.x >> 6, l = threadIdx.x & 63;
  const size_t row = (size_t)blockIdx.x*4 + w;
  float vx[3][4]; float s1 = 0.f, s2 = 0.f;
  #pragma unroll
  for (int c = 0; c < 3; ++c) {
    ushort4 u0 = reinterpret_cast<const ushort4*>(xb + row*D_)[l + 64*c];
    vx[c][0] = b2f(u0.x); vx[c][1] = b2f(u0.y); vx[c][2] = b2f(u0.z); vx[c][3] = b2f(u0.w);
    #pragma unroll
    for (int p = 1; p < NP; ++p) {
      ushort4 up = reinterpret_cast<const ushort4*>(xb + (size_t)p*NT_*D_ + row*D_)[l + 64*c];
      vx[c][0] += b2f(up.x); vx[c][1] += b2f(up.y); vx[c][2] += b2f(up.z); vx[c][3] += b2f(up.w);
    }
    if constexpr (EXTRA) {
      ushort4 ur = reinterpret_cast<const ushort4*>(resid + row*D_)[l + 64*c];
      float4 bb = reinterpret_cast<const float4*>(bias2)[l + 64*c];
      vx[c][0] += b2f(ur.x) + bb.x; vx[c][1] += b2f(ur.y) + bb.y;
      vx[c][2] += b2f(ur.z) + bb.z; vx[c][3] += b2f(ur.w) + bb.w;
    }
    #pragma unroll
    for (int e = 0; e < 4; ++e) { s1 += vx[c][e]; s2 += vx[c][e]*vx[c][e]; }
  }
  s1 = wsum(s1); s2 = wsum(s2);
  const float mean = s1 * (1.f/768.f);
  const float var  = s2 * (1.f/768.f) - mean*mean;
  const float rs   = rsqrtf(var + 1e-5f);
  const float4* gp = reinterpret_cast<const float4*>(g);
  const float4* bp = reinterpret_cast<const float4*>(bta);
  #pragma unroll
  for (int c = 0; c < 3; ++c) {
    float4 gg = gp[l + 64*c], bb = bp[l + 64*c];
    float r0 = (vx[c][0] - mean)*rs*gg.x + bb.x;
    float r1 = (vx[c][1] - mean)*rs*gg.y + bb.y;
    float r2 = (vx[c][2] - mean)*rs*gg.z + bb.z;
    float r3 = (vx[c][3] - mean)*rs*gg.w + bb.w;
    if constexpr (WF32) {
      float4 r; r.x = r0; r.y = r1; r.z = r2; r.w = r3;
      reinterpret_cast<float4*>(ho + row*D_)[l + 64*c] = r;
    }
    ushort4 u; u.x = f2b(r0); u.y = f2b(r1); u.z = f2b(r2); u.w = f2b(r3);
    reinterpret_cast<ushort4*>(hb + row*D_)[l + 64*c] = u;
  }
}

extern "C" void kernel_launch(void* const* d_in, const int* in_sizes, int n_in,
                              void* d_out, int out_size, void* d_ws, size_t ws_size,
                              hipStream_t stream)
{
  const int*   x_ids = (const int*)  d_in[0];
  const float* emb   = (const float*)d_in[1];
  const float* Wq    = (const float*)d_in[2];
  const float* bq    = (const float*)d_in[3];
  const float* Wk    = (const float*)d_in[4];
  const float* bk    = (const float*)d_in[5];
  const float* Wv    = (const float*)d_in[6];
  const float* bv    = (const float*)d_in[7];
  const float* Wo    = (const float*)d_in[8];
  const float* bo    = (const float*)d_in[9];
  const float* g1    = (const float*)d_in[10];
  const float* bn1   = (const float*)d_in[11];
  const float* W1    = (const float*)d_in[12];
  const float* bw1   = (const float*)d_in[13];
  const float* W2    = (const float*)d_in[14];
  const float* bw2   = (const float*)d_in[15];
  const float* g2    = (const float*)d_in[16];
  const float* bn2   = (const float*)d_in[17];

  char* ws = (char*)d_ws;
  size_t off = 0;
  auto alloc = [&](size_t bytes) -> void* {
    void* p = ws + off; off += (bytes + 255) & ~((size_t)255); return p;
  };
  unsigned short* WqkvT = (unsigned short*)alloc((size_t)L_*DQKV_*D_*2);
  unsigned short* WoT = (unsigned short*)alloc((size_t)L_*D_*D_*2);
  unsigned short* W1T = (unsigned short*)alloc((size_t)L_*D_*F_*2);
  unsigned short* W2T = (unsigned short*)alloc((size_t)L_*D_*F_*2);
  float*          bqkv= (float*)         alloc((size_t)L_*DQKV_*4);
  float*          pe  = (float*)         alloc((size_t)S_*D_*4);
  unsigned short* hb  = (unsigned short*)alloc((size_t)NT_*D_*2);
  unsigned short* qkv = (unsigned short*)alloc((size_t)NT_*DQKV_*2);
  unsigned short* vt  = (unsigned short*)alloc((size_t)BH_*DK_*S_*2);
  unsigned short* attnb = (unsigned short*)alloc((size_t)NT_*D_*2);
  unsigned short* yb  = (unsigned short*)alloc((size_t)NT_*D_*2);
  unsigned short* f1b = (unsigned short*)alloc((size_t)NT_*F_*2);
  unsigned short* y2pb= (unsigned short*)alloc((size_t)4*NT_*D_*2);  // FFN2 split-K=4 partials
  if (off > ws_size) return;

  // weight convert+transpose (per call; graph-safe)
  wconvqkv_kernel<<<dim3(24,12,L_*3), dim3(32,8), 0, stream>>>(Wq, Wk, Wv, WqkvT);
  wconv_kernel<<<dim3(24,12,L_), dim3(32,8), 0, stream>>>(Wo, WoT, D_, D_, (size_t)D_*D_, 0);
  wconv_kernel<<<dim3(96,12,L_), dim3(32,8), 0, stream>>>(W1, W1T, D_, F_, (size_t)D_*F_, 0);
  wconv_kernel<<<dim3(24,48,L_), dim3(32,8), 0, stream>>>(W2, W2T, F_, D_, (size_t)F_*D_, 0);
  bcat_kernel<<<dim3((L_*DQKV_+255)/256), 256, 0, stream>>>(bq, bk, bv, bqkv);

  pe_kernel<<<dim3(S_*384/256), 256, 0, stream>>>(pe);
  embed_kernel<<<dim3(NT_*192/256), 256, 0, stream>>>(x_ids, emb, pe, hb);

  for (int l = 0; l < L_; ++l) {
    const unsigned short* wqkvT = WqkvT + (size_t)l*DQKV_*D_;
    const unsigned short* woT = WoT + (size_t)l*D_*D_;
    const unsigned short* w1T = W1T + (size_t)l*D_*F_;
    const unsigned short* w2T = W2T + (size_t)l*D_*F_;

    // QKV fused: [NT,768] @ [768,2304] -> qkv bf16   (18*32 = 576 blocks)
    gemm_kernel<128,1,true,false,false><<<576, 256, 0, stream>>>(
        hb, wqkvT, bqkv + l*DQKV_, nullptr, qkv, NT_, DQKV_, D_);

    vtrans_kernel<<<dim3(16,2,BH_), dim3(32,8), 0, stream>>>(qkv + 2*D_, vt, DQKV_);
    fattn_kernel<<<dim3(S_/128, BH_), 256, 0, stream>>>(qkv, vt, attnb);

    // O-proj + bias + bf16 residual -> yb bf16   (384 blocks, TN=64)
    gemm_kernel<64,1,true,true,false><<<384, 256, 0, stream>>>(
        attnb, woT, bo + l*D_, hb, yb, NT_, D_, D_);
    ln_kernel<1,false,false><<<dim3(NT_/4), 256, 0, stream>>>(yb, nullptr, nullptr,
        g1 + l*D_, bn1 + l*D_, nullptr, hb);

    // FFN1 + bias + relu -> f1b bf16   (24*32 = 768 blocks)
    gemm_kernel<128,1,true,false,true><<<768, 256, 0, stream>>>(
        hb, w1T, bw1 + l*F_, nullptr, f1b, NT_, F_, D_);
    // FFN2 split-K=4 bf16 partials (bias/resid folded into ln2)   (6*32*4 = 768 blocks)
    gemm_kernel<128,4,false,false,false><<<768, 256, 0, stream>>>(
        f1b, w2T, nullptr, nullptr, y2pb, NT_, D_, F_);

    if (l == L_-1)
      ln_kernel<4,true,true><<<dim3(NT_/4), 256, 0, stream>>>(y2pb, hb, bw2 + l*D_,
          g2 + l*D_, bn2 + l*D_, (float*)d_out, hb);
    else
      ln_kernel<4,true,false><<<dim3(NT_/4), 256, 0, stream>>>(y2pb, hb, bw2 + l*D_,
          g2 + l*D_, bn2 + l*D_, nullptr, hb);
  }
}

// Round 12
// 642.773 us; speedup vs baseline: 1.1372x; 1.1372x over previous
//
#include <hip/hip_runtime.h>
#include <stdint.h>

#define B_ 8
#define S_ 512
#define D_ 768
#define H_ 12
#define DK_ 64
#define F_ 3072
#define L_ 4
#define NT_ (B_*S_)     // 4096 tokens
#define BH_ (B_*H_)     // 96 (b,h) pairs
#define DQKV_ 2304      // fused q|k|v width

typedef __bf16 bf16x8 __attribute__((ext_vector_type(8)));
typedef float f32x4 __attribute__((ext_vector_type(4)));

static __device__ __forceinline__ unsigned short f2b(float f){
  union { float f; unsigned u; } x; x.f = f;
  unsigned r = x.u + 0x7fffu + ((x.u >> 16) & 1u);   // RNE, finite values
  return (unsigned short)(r >> 16);
}
static __device__ __forceinline__ float b2f(unsigned short u){
  union { unsigned u; float f; } x; x.u = ((unsigned)u) << 16; return x.f;
}

static __device__ __forceinline__ void gload16(const void* g, void* l){
  __builtin_amdgcn_global_load_lds((const __attribute__((address_space(1))) void*)g,
                                   (__attribute__((address_space(3))) void*)l, 16, 0, 0);
}

static __device__ __forceinline__ float wsum(float v){
  #pragma unroll
  for (int off = 32; off; off >>= 1) v += __shfl_xor(v, off);
  return v;
}

// ---------------- weight transpose + f32->bf16: in[R][C] -> out[(rowBase+c)*R + r]
// 64-row output tiles, ushort2 lane writes -> 128B contiguous store segments.
__global__ void wconv_kernel(const float* __restrict__ in, unsigned short* __restrict__ out,
                             int R, int C, size_t outLS, int rowBase){
  __shared__ float tile[64][33];
  const int l = blockIdx.z;
  in  += (size_t)l*R*C;
  out += (size_t)l*outLS;
  const int c0 = blockIdx.x*32, r0 = blockIdx.y*64;
  const int tx = threadIdx.x, ty = threadIdx.y;  // (32,8)
  #pragma unroll
  for (int i = 0; i < 8; ++i)
    tile[ty+8*i][tx] = in[(size_t)(r0+ty+8*i)*C + c0+tx];
  __syncthreads();
  #pragma unroll
  for (int p = 0; p < 4; ++p) {
    const int c = p*8 + ty;
    ushort2 u;
    u.x = f2b(tile[tx*2][c]);
    u.y = f2b(tile[tx*2+1][c]);
    *reinterpret_cast<ushort2*>(&out[(size_t)(rowBase + c0 + c)*R + r0 + tx*2]) = u;
  }
}

// ---------------- fused q|k|v weight transpose (same layout trick)
__global__ void wconvqkv_kernel(const float* __restrict__ Wq, const float* __restrict__ Wk,
                                const float* __restrict__ Wv, unsigned short* __restrict__ out){
  __shared__ float tile[64][33];
  const int z = blockIdx.z;
  const int l = z / 3, which = z % 3;
  const float* in = (which == 0 ? Wq : which == 1 ? Wk : Wv) + (size_t)l*D_*D_;
  unsigned short* o = out + (size_t)l*DQKV_*D_;
  const int rowBase = which*D_;
  const int c0 = blockIdx.x*32, r0 = blockIdx.y*64;
  const int tx = threadIdx.x, ty = threadIdx.y;  // (32,8)
  #pragma unroll
  for (int i = 0; i < 8; ++i)
    tile[ty+8*i][tx] = in[(size_t)(r0+ty+8*i)*D_ + c0+tx];
  __syncthreads();
  #pragma unroll
  for (int p = 0; p < 4; ++p) {
    const int c = p*8 + ty;
    ushort2 u;
    u.x = f2b(tile[tx*2][c]);
    u.y = f2b(tile[tx*2+1][c]);
    *reinterpret_cast<ushort2*>(&o[(size_t)(rowBase + c0 + c)*D_ + r0 + tx*2]) = u;
  }
}

// ---------------- concat q|k|v biases -> [L][2304]
__global__ void bcat_kernel(const float* __restrict__ bq, const float* __restrict__ bk,
                            const float* __restrict__ bv, float* __restrict__ out){
  int i = blockIdx.x*256 + threadIdx.x;
  if (i >= L_*DQKV_) return;
  int l = i / DQKV_, c = i % DQKV_;
  float v = (c < D_) ? bq[l*D_ + c] : (c < 2*D_) ? bk[l*D_ + c - D_] : bv[l*D_ + c - 2*D_];
  out[i] = v;
}

// ---------------- sinusoidal PE table [S][D]
__global__ __launch_bounds__(256) void pe_kernel(float* __restrict__ pe){
  int u = blockIdx.x*256 + threadIdx.x;   // S*384 pairs
  if (u >= S_*384) return;
  int dp = u % 384, s = u / 384;
  int d0 = dp*2;
  float div = __expf((float)d0 * (-9.210340371976184f / 768.0f));
  float ang = (float)s * div;
  pe[(size_t)s*D_ + d0]     = sinf(ang);
  pe[(size_t)s*D_ + d0 + 1] = cosf(ang);
}

// ---------------- embedding + PE table; writes bf16 hb (residual stream is bf16)
__global__ __launch_bounds__(256) void embed_kernel(const int* __restrict__ ids,
                                                    const float* __restrict__ emb,
                                                    const float* __restrict__ pe,
                                                    unsigned short* __restrict__ hb){
  int u = blockIdx.x*256 + threadIdx.x;   // NT*192 float4 units
  if (u >= NT_*192) return;
  int c = u % 192, t = u / 192, s = t % S_;
  int id = ids[t];
  float4 e = reinterpret_cast<const float4*>(emb + (size_t)id*D_)[c];
  float4 p = reinterpret_cast<const float4*>(pe  + (size_t)s*D_)[c];
  ushort4 ub; ub.x = f2b(e.x+p.x); ub.y = f2b(e.y+p.y); ub.z = f2b(e.z+p.z); ub.w = f2b(e.w+p.w);
  reinterpret_cast<ushort4*>(hb + (size_t)t*D_)[c] = ub;
}

// ---------------- 128xTN bf16 MFMA GEMM, ring-3 LDS, counted vmcnt (T4), raw barriers
// Schedule per iter t: vmcnt(own tile-t loads) -> s_barrier -> ds_read frags ->
// lgkmcnt(0)+sched_barrier -> s_barrier (buf dead) -> issue stage(t+3) -> MFMA.
// Loads stay 3 tiles deep across barriers; tail steps wait 2L -> L -> 0.
// NOTE (R9): SQ_LDS_BANK_CONFLICT == 4 cyc/ds_read_b128 is intrinsic (2-way aliasing,
// free per m136) — not a fixable conflict. NOTE (R8/R10/R11): reg-frag dbuf and BK=64
// single-barrier both REGRESS; this ring-3 structure is the local optimum at these shapes.
// A:[M][K], Bt:[N][K], XCD-swizzled 1D grid. KS: split-K. Output bf16 at outp+ks*M*N.
template<int TN, int KS, bool BIAS, bool RES, bool RELU>
__global__ __launch_bounds__(256)
void gemm_kernel(const unsigned short* __restrict__ A,
                 const unsigned short* __restrict__ Bt,
                 const float* __restrict__ bias,
                 const unsigned short* __restrict__ residB,
                 unsigned short* __restrict__ outp,
                 int M, int N, int K)
{
  constexpr int WN = TN/2;          // wave cols
  constexpr int JF = WN/16;         // n-frags per wave
  constexpr int SLOTS = (128+TN)/64; // gload16 per thread per K-tile (A:2, B:TN/64)
  __shared__ __attribute__((aligned(16))) unsigned short As[3][128*32];
  __shared__ __attribute__((aligned(16))) unsigned short Bs[3][TN*32];
  const int tid = threadIdx.x;
  const int w = tid >> 6, l = tid & 63;
  const int wm = w >> 1, wn = w & 1;
  const int c16 = l & 15, g = l >> 4;

  // bijective XCD swizzle (requires gridDim.x % 8 == 0)
  const int nwg = gridDim.x;
  const int cpx = nwg >> 3;
  const int sw  = (blockIdx.x & 7)*cpx + (blockIdx.x >> 3);
  const int nbx = N/TN;
  const int nby = M/128;
  const int bx = sw % nbx;
  const int t2 = sw / nbx;
  const int by = t2 % nby;
  const int ks = t2 / nby;          // 0..KS-1
  const int bm = by*128, bn = bx*TN;
  const int Klen = K / KS;
  const int kBeg = ks*Klen;
  const int nk = Klen >> 5;         // all call sites have nk >= 3

  auto stage = [&](int buf, int k0){
    #pragma unroll
    for (int s = 0; s < SLOTS; ++s) {
      const int base = s*4096 + w*1024;       // block-linear byte base (wave-uniform)
      const int x    = base + l*16;           // this lane's linear LDS byte
      if (s < 2) {                            // A: 8KB (64B = one 32-bf16 row)
        const int row  = x >> 6;
        const int csrc = ((x >> 4) & 3) ^ ((row >> 2) & 3);   // inverse swizzle on source
        gload16(A + (size_t)(bm+row)*K + k0 + csrc*8, (void*)(As[buf] + base/2));
      } else {                                // B
        const int o2   = x - 8192;
        const int row  = o2 >> 6;
        const int csrc = ((o2 >> 4) & 3) ^ ((row >> 2) & 3);
        gload16(Bt + (size_t)(bn+row)*K + k0 + csrc*8, (void*)(Bs[buf] + (base-8192)/2));
      }
    }
  };

  f32x4 acc[4][JF] = {};
  const int cswz = (g ^ (c16 >> 2)) * 8;      // swizzled k-chunk (bf16 units)

  // prologue: 3 tiles in flight (nk >= 3 at every call site)
  stage(0, kBeg);
  stage(1, kBeg + 32);
  stage(2, kBeg + 64);

  for (int t = 0; t < nk; ++t) {
    const int cur = t % 3;
    // wait until own share of tile t landed; keep newer tiles' loads in flight
    const int rem = nk - 1 - t;               // tiles staged after t: min(rem,2)
    if constexpr (SLOTS == 4) {
      if (rem >= 2)      asm volatile("s_waitcnt vmcnt(8)" ::: "memory");
      else if (rem == 1) asm volatile("s_waitcnt vmcnt(4)" ::: "memory");
      else               asm volatile("s_waitcnt vmcnt(0)" ::: "memory");
    } else {
      if (rem >= 2)      asm volatile("s_waitcnt vmcnt(6)" ::: "memory");
      else if (rem == 1) asm volatile("s_waitcnt vmcnt(3)" ::: "memory");
      else               asm volatile("s_waitcnt vmcnt(0)" ::: "memory");
    }
    __builtin_amdgcn_s_barrier();             // barrier 1: tile t fully in LDS
    __builtin_amdgcn_sched_barrier(0);

    bf16x8 af[4], bfr[JF];
    #pragma unroll
    for (int i = 0; i < 4; ++i)
      af[i]  = *reinterpret_cast<const bf16x8*>(&As[cur][(wm*64 + i*16 + c16)*32 + cswz]);
    #pragma unroll
    for (int j = 0; j < JF; ++j)
      bfr[j] = *reinterpret_cast<const bf16x8*>(&Bs[cur][(wn*WN + j*16 + c16)*32 + cswz]);
    asm volatile("s_waitcnt lgkmcnt(0)" ::: "memory");
    __builtin_amdgcn_sched_barrier(0);
    __builtin_amdgcn_s_barrier();             // barrier 2: buf[cur] dead everywhere

    if (t + 3 < nk) stage(cur, kBeg + (t+3)*32);   // refill ring; latency hides under MFMA

    __builtin_amdgcn_s_setprio(1);
    #pragma unroll
    for (int i = 0; i < 4; ++i)
      #pragma unroll
      for (int j = 0; j < JF; ++j)
        acc[i][j] = __builtin_amdgcn_mfma_f32_16x16x32_bf16(af[i], bfr[j], acc[i][j], 0, 0, 0);
    __builtin_amdgcn_s_setprio(0);
  }

  unsigned short* outB = outp + (size_t)ks*M*N;
  #pragma unroll
  for (int i = 0; i < 4; ++i) {
    #pragma unroll
    for (int e = 0; e < 4; ++e) {
      const int row = bm + wm*64 + i*16 + (l>>4)*4 + e;
      #pragma unroll
      for (int j = 0; j < JF; ++j) {
        const int col = bn + wn*WN + j*16 + (l&15);
        float v = acc[i][j][e];
        if constexpr (BIAS) v += bias[col];
        if constexpr (RES)  v += b2f(residB[(size_t)row*N + col]);
        if constexpr (RELU) v = fmaxf(v, 0.f);
        outB[(size_t)row*N + col] = f2b(v);
      }
    }
  }
}

// ---------------- V transpose per head: src[b,s,ld-strided, head hh] -> vt[(b*H+h), d, s]
__global__ void vtrans_kernel(const unsigned short* __restrict__ v,
                              unsigned short* __restrict__ vt, int ld){
  __shared__ unsigned short tile[32][33];
  const int z = blockIdx.z; const int b = z / H_, hh = z % H_;
  const int j0 = blockIdx.x*32;   // seq
  const int d0 = blockIdx.y*32;   // within head
  const int tx = threadIdx.x, ty = threadIdx.y;
  const unsigned short* src = v + (size_t)b*S_*ld + hh*DK_;
  #pragma unroll
  for (int i = 0; i < 4; ++i)
    tile[ty+8*i][tx] = src[(size_t)(j0+ty+8*i)*ld + d0+tx];
  __syncthreads();
  unsigned short* dst = vt + (size_t)z*DK_*S_;
  #pragma unroll
  for (int i = 0; i < 4; ++i)
    dst[(size_t)(d0+ty+8*i)*S_ + j0+tx] = tile[tx][ty+8*i];
}

// ---------------- fused flash attention: QK^T (swapped) -> online softmax -> PV
// Block: 4 waves, each wave owns 32 q-rows. Grid: (S/128, BH).
// Q,K direct from qkv (ld=DQKV); V from vt [z][d][s]; out attnb [NT][D] bf16.
__global__ __launch_bounds__(256)
void fattn_kernel(const unsigned short* __restrict__ qkv,
                  const unsigned short* __restrict__ vt,
                  unsigned short* __restrict__ o)
{
  __shared__ __attribute__((aligned(16))) unsigned short Plds[4*4096]; // 4 waves x 8KB
  const int tid = threadIdx.x;
  const int w = tid >> 6, l = tid & 63;
  const int g = l >> 4, c16 = l & 15;
  const int z = blockIdx.y; const int b = z / H_, hh = z % H_;
  const int q0 = blockIdx.x*128 + w*32;

  const unsigned short* qp = qkv + (size_t)b*S_*DQKV_ + hh*DK_;
  const unsigned short* kp = qp + D_;
  const unsigned short* vv = vt + (size_t)z*DK_*S_;
  char* pbase = (char*)Plds + w*8192;

  // hoist Q fragments (B-operand: cols = q rows)
  bf16x8 qf[2][2];
  #pragma unroll
  for (int jf = 0; jf < 2; ++jf)
    #pragma unroll
    for (int kc = 0; kc < 2; ++kc)
      qf[jf][kc] = *reinterpret_cast<const bf16x8*>(qp + (size_t)(q0 + jf*16 + c16)*DQKV_ + kc*32 + g*8);

  f32x4 acc_o[2][4] = {};
  float m_run[2] = {-1e30f, -1e30f};
  float l_run[2] = {0.f, 0.f};

  for (int kb = 0; kb < S_/128; ++kb) {
    // ---- scores: acc_s[kt][jf] = K-tile x Q  (C rows = k, cols = q)
    f32x4 acc_s[8][2] = {};
    #pragma unroll
    for (int kt = 0; kt < 8; ++kt) {
      bf16x8 af0 = *reinterpret_cast<const bf16x8*>(kp + (size_t)(kb*128 + kt*16 + c16)*DQKV_ + 0*32 + g*8);
      bf16x8 af1 = *reinterpret_cast<const bf16x8*>(kp + (size_t)(kb*128 + kt*16 + c16)*DQKV_ + 1*32 + g*8);
      #pragma unroll
      for (int jf = 0; jf < 2; ++jf) {
        acc_s[kt][jf] = __builtin_amdgcn_mfma_f32_16x16x32_bf16(af0, qf[jf][0], acc_s[kt][jf], 0, 0, 0);
        acc_s[kt][jf] = __builtin_amdgcn_mfma_f32_16x16x32_bf16(af1, qf[jf][1], acc_s[kt][jf], 0, 0, 0);
      }
    }
    // ---- online softmax per q (= col lane c16, per jf)
    float fac[2];
    #pragma unroll
    for (int jf = 0; jf < 2; ++jf) {
      float vmax = -1e30f;
      #pragma unroll
      for (int kt = 0; kt < 8; ++kt)
        #pragma unroll
        for (int e = 0; e < 4; ++e) {
          acc_s[kt][jf][e] *= 0.125f;
          vmax = fmaxf(vmax, acc_s[kt][jf][e]);
        }
      vmax = fmaxf(vmax, __shfl_xor(vmax, 16));
      vmax = fmaxf(vmax, __shfl_xor(vmax, 32));
      const float m_new = fmaxf(m_run[jf], vmax);
      fac[jf] = __expf(m_run[jf] - m_new);
      float ps = 0.f;
      #pragma unroll
      for (int kt = 0; kt < 8; ++kt)
        #pragma unroll
        for (int e = 0; e < 4; ++e) {
          float p = __expf(acc_s[kt][jf][e] - m_new);
          acc_s[kt][jf][e] = p;
          ps += p;
        }
      ps += __shfl_xor(ps, 16);
      ps += __shfl_xor(ps, 32);
      l_run[jf] = l_run[jf]*fac[jf] + ps;
      m_run[jf] = m_new;
      // write P row (q = jf*16+c16) to LDS, bf16, linear-in-k, XOR-swizzled
      const int q = jf*16 + c16;
      #pragma unroll
      for (int kt = 0; kt < 8; ++kt) {
        uint2 val;
        val.x = (unsigned)f2b(acc_s[kt][jf][0]) | ((unsigned)f2b(acc_s[kt][jf][1]) << 16);
        val.y = (unsigned)f2b(acc_s[kt][jf][2]) | ((unsigned)f2b(acc_s[kt][jf][3]) << 16);
        int off = (q*256 + kt*32 + g*8) ^ ((q & 7) << 4);
        *reinterpret_cast<uint2*>(pbase + off) = val;
      }
    }
    // ---- rescale O by fac (per q-row; redistribute col->row lanes via shfl)
    #pragma unroll
    for (int jr = 0; jr < 2; ++jr)
      #pragma unroll
      for (int e = 0; e < 4; ++e) {
        const float fr = __shfl(fac[jr], g*4 + e);
        #pragma unroll
        for (int jd = 0; jd < 4; ++jd)
          acc_o[jr][jd][e] *= fr;
      }
    // ---- PV: A = P from LDS, B = Vt rows (d-major) from global
    #pragma unroll
    for (int kc = 0; kc < 4; ++kc) {
      bf16x8 pa[2], vfr[4];
      #pragma unroll
      for (int jf = 0; jf < 2; ++jf) {
        const int q = jf*16 + c16;
        int off = (q*256 + kc*64 + g*16) ^ ((q & 7) << 4);
        pa[jf] = *reinterpret_cast<const bf16x8*>(pbase + off);
      }
      #pragma unroll
      for (int jd = 0; jd < 4; ++jd)
        vfr[jd] = *reinterpret_cast<const bf16x8*>(vv + (size_t)(jd*16 + c16)*S_ + kb*128 + kc*32 + g*8);
      #pragma unroll
      for (int jf = 0; jf < 2; ++jf)
        #pragma unroll
        for (int jd = 0; jd < 4; ++jd)
          acc_o[jf][jd] = __builtin_amdgcn_mfma_f32_16x16x32_bf16(pa[jf], vfr[jd], acc_o[jf][jd], 0, 0, 0);
    }
  }

  // ---- normalize + write O
  float invl[2] = {1.f/l_run[0], 1.f/l_run[1]};
  unsigned short* ob = o + (size_t)b*S_*D_ + hh*DK_;
  #pragma unroll
  for (int jr = 0; jr < 2; ++jr)
    #pragma unroll
    for (int e = 0; e < 4; ++e) {
      const float ir = __shfl(invl[jr], g*4 + e);
      const int r = q0 + jr*16 + g*4 + e;
      #pragma unroll
      for (int jd = 0; jd < 4; ++jd)
        ob[(size_t)r*D_ + jd*16 + c16] = f2b(acc_o[jr][jd][e] * ir);
    }
}

// ---------------- LayerNorm: wave per row. x = sum of NP bf16 partials (stride NT*D);
// EXTRA adds bf16 resid + broadcast f32 bias2. Writes bf16 hb; WF32 also writes f32 ho.
template<int NP, bool EXTRA, bool WF32>
__global__ __launch_bounds__(256)
void ln_kernel(const unsigned short* __restrict__ xb,
               const unsigned short* __restrict__ resid, const float* __restrict__ bias2,
               const float* __restrict__ g, const float* __restrict__ bta,
               float* __restrict__ ho, unsigned short* __restrict__ hb)
{
  const int w = threadIdx.x >> 6, l = threadIdx.x & 63;
  const size_t row = (size_t)blockIdx.x*4 + w;
  float vx[3][4]; float s1 = 0.f, s2 = 0.f;
  #pragma unroll
  for (int c = 0; c < 3; ++c) {
    ushort4 u0 = reinterpret_cast<const ushort4*>(xb + row*D_)[l + 64*c];
    vx[c][0] = b2f(u0.x); vx[c][1] = b2f(u0.y); vx[c][2] = b2f(u0.z); vx[c][3] = b2f(u0.w);
    #pragma unroll
    for (int p = 1; p < NP; ++p) {
      ushort4 up = reinterpret_cast<const ushort4*>(xb + (size_t)p*NT_*D_ + row*D_)[l + 64*c];
      vx[c][0] += b2f(up.x); vx[c][1] += b2f(up.y); vx[c][2] += b2f(up.z); vx[c][3] += b2f(up.w);
    }
    if constexpr (EXTRA) {
      ushort4 ur = reinterpret_cast<const ushort4*>(resid + row*D_)[l + 64*c];
      float4 bb = reinterpret_cast<const float4*>(bias2)[l + 64*c];
      vx[c][0] += b2f(ur.x) + bb.x; vx[c][1] += b2f(ur.y) + bb.y;
      vx[c][2] += b2f(ur.z) + bb.z; vx[c][3] += b2f(ur.w) + bb.w;
    }
    #pragma unroll
    for (int e = 0; e < 4; ++e) { s1 += vx[c][e]; s2 += vx[c][e]*vx[c][e]; }
  }
  s1 = wsum(s1); s2 = wsum(s2);
  const float mean = s1 * (1.f/768.f);
  const float var  = s2 * (1.f/768.f) - mean*mean;
  const float rs   = rsqrtf(var + 1e-5f);
  const float4* gp = reinterpret_cast<const float4*>(g);
  const float4* bp = reinterpret_cast<const float4*>(bta);
  #pragma unroll
  for (int c = 0; c < 3; ++c) {
    float4 gg = gp[l + 64*c], bb = bp[l + 64*c];
    float r0 = (vx[c][0] - mean)*rs*gg.x + bb.x;
    float r1 = (vx[c][1] - mean)*rs*gg.y + bb.y;
    float r2 = (vx[c][2] - mean)*rs*gg.z + bb.z;
    float r3 = (vx[c][3] - mean)*rs*gg.w + bb.w;
    if constexpr (WF32) {
      float4 r; r.x = r0; r.y = r1; r.z = r2; r.w = r3;
      reinterpret_cast<float4*>(ho + row*D_)[l + 64*c] = r;
    }
    ushort4 u; u.x = f2b(r0); u.y = f2b(r1); u.z = f2b(r2); u.w = f2b(r3);
    reinterpret_cast<ushort4*>(hb + row*D_)[l + 64*c] = u;
  }
}

extern "C" void kernel_launch(void* const* d_in, const int* in_sizes, int n_in,
                              void* d_out, int out_size, void* d_ws, size_t ws_size,
                              hipStream_t stream)
{
  const int*   x_ids = (const int*)  d_in[0];
  const float* emb   = (const float*)d_in[1];
  const float* Wq    = (const float*)d_in[2];
  const float* bq    = (const float*)d_in[3];
  const float* Wk    = (const float*)d_in[4];
  const float* bk    = (const float*)d_in[5];
  const float* Wv    = (const float*)d_in[6];
  const float* bv    = (const float*)d_in[7];
  const float* Wo    = (const float*)d_in[8];
  const float* bo    = (const float*)d_in[9];
  const float* g1    = (const float*)d_in[10];
  const float* bn1   = (const float*)d_in[11];
  const float* W1    = (const float*)d_in[12];
  const float* bw1   = (const float*)d_in[13];
  const float* W2    = (const float*)d_in[14];
  const float* bw2   = (const float*)d_in[15];
  const float* g2    = (const float*)d_in[16];
  const float* bn2   = (const float*)d_in[17];

  char* ws = (char*)d_ws;
  size_t off = 0;
  auto alloc = [&](size_t bytes) -> void* {
    void* p = ws + off; off += (bytes + 255) & ~((size_t)255); return p;
  };
  unsigned short* WqkvT = (unsigned short*)alloc((size_t)L_*DQKV_*D_*2);
  unsigned short* WoT = (unsigned short*)alloc((size_t)L_*D_*D_*2);
  unsigned short* W1T = (unsigned short*)alloc((size_t)L_*D_*F_*2);
  unsigned short* W2T = (unsigned short*)alloc((size_t)L_*D_*F_*2);
  float*          bqkv= (float*)         alloc((size_t)L_*DQKV_*4);
  float*          pe  = (float*)         alloc((size_t)S_*D_*4);
  unsigned short* hb  = (unsigned short*)alloc((size_t)NT_*D_*2);
  unsigned short* qkv = (unsigned short*)alloc((size_t)NT_*DQKV_*2);
  unsigned short* vt  = (unsigned short*)alloc((size_t)BH_*DK_*S_*2);
  unsigned short* attnb = (unsigned short*)alloc((size_t)NT_*D_*2);
  unsigned short* yb  = (unsigned short*)alloc((size_t)NT_*D_*2);
  unsigned short* f1b = (unsigned short*)alloc((size_t)NT_*F_*2);
  unsigned short* y2pb= (unsigned short*)alloc((size_t)4*NT_*D_*2);  // FFN2 split-K=4 partials (bf16)
  if (off > ws_size) return;

  // weight convert+transpose (per call; graph-safe)
  wconvqkv_kernel<<<dim3(24,12,L_*3), dim3(32,8), 0, stream>>>(Wq, Wk, Wv, WqkvT);
  wconv_kernel<<<dim3(24,12,L_), dim3(32,8), 0, stream>>>(Wo, WoT, D_, D_, (size_t)D_*D_, 0);
  wconv_kernel<<<dim3(96,12,L_), dim3(32,8), 0, stream>>>(W1, W1T, D_, F_, (size_t)D_*F_, 0);
  wconv_kernel<<<dim3(24,48,L_), dim3(32,8), 0, stream>>>(W2, W2T, F_, D_, (size_t)F_*D_, 0);
  bcat_kernel<<<dim3((L_*DQKV_+255)/256), 256, 0, stream>>>(bq, bk, bv, bqkv);

  pe_kernel<<<dim3(S_*384/256), 256, 0, stream>>>(pe);
  embed_kernel<<<dim3(NT_*192/256), 256, 0, stream>>>(x_ids, emb, pe, hb);

  for (int l = 0; l < L_; ++l) {
    const unsigned short* wqkvT = WqkvT + (size_t)l*DQKV_*D_;
    const unsigned short* woT = WoT + (size_t)l*D_*D_;
    const unsigned short* w1T = W1T + (size_t)l*D_*F_;
    const unsigned short* w2T = W2T + (size_t)l*D_*F_;

    // QKV fused: [NT,768] @ [768,2304] -> qkv bf16   (18*32 = 576 blocks)
    gemm_kernel<128,1,true,false,false><<<576, 256, 0, stream>>>(
        hb, wqkvT, bqkv + l*DQKV_, nullptr, qkv, NT_, DQKV_, D_);

    vtrans_kernel<<<dim3(16,2,BH_), dim3(32,8), 0, stream>>>(qkv + 2*D_, vt, DQKV_);
    fattn_kernel<<<dim3(S_/128, BH_), 256, 0, stream>>>(qkv, vt, attnb);

    // O-proj + bias + bf16 residual -> yb bf16   (384 blocks, TN=64)
    gemm_kernel<64,1,true,true,false><<<384, 256, 0, stream>>>(
        attnb, woT, bo + l*D_, hb, yb, NT_, D_, D_);
    ln_kernel<1,false,false><<<dim3(NT_/4), 256, 0, stream>>>(yb, nullptr, nullptr,
        g1 + l*D_, bn1 + l*D_, nullptr, hb);

    // FFN1 + bias + relu -> f1b bf16   (24*32 = 768 blocks)
    gemm_kernel<128,1,true,false,true><<<768, 256, 0, stream>>>(
        hb, w1T, bw1 + l*F_, nullptr, f1b, NT_, F_, D_);
    // FFN2 split-K=4 bf16 partials (bias/resid folded into ln2)   (6*32*4 = 768 blocks)
    gemm_kernel<128,4,false,false,false><<<768, 256, 0, stream>>>(
        f1b, w2T, nullptr, nullptr, y2pb, NT_, D_, F_);

    if (l == L_-1)
      ln_kernel<4,true,true><<<dim3(NT_/4), 256, 0, stream>>>(y2pb, hb, bw2 + l*D_,
          g2 + l*D_, bn2 + l*D_, (float*)d_out, hb);
    else
      ln_kernel<4,true,false><<<dim3(NT_/4), 256, 0, stream>>>(y2pb, hb, bw2 + l*D_,
          g2 + l*D_, bn2 + l*D_, nullptr, hb);
  }
}